// Round 2
// 205.588 us; speedup vs baseline: 1.0260x; 1.0260x over previous
//
#include <hip/hip_runtime.h>
#include <math.h>

// CropRoi — R8b: async global->LDS staging + compacted staging domain.
// (R8 resubmit; the R8 bench died at container level with no diagnostic —
// infra flake, not kernel evidence. Only change vs R8: the magic-divisor
// LUT is computed inline per block instead of living in __constant__.)
//
// R7 (210.5 us measured / ~20 us isolated) staged via VGPR round-trip with a
// per-iteration waitcnt (dynamic trip count -> no unroll -> ~2.4 serialized
// L3 latencies/thread) and iterated the full Lz*17*5 slot domain (~35% of
// slots dead when Ly<17). R8:
//   - __builtin_amdgcn_global_load_lds (16B): fire-and-forget staging, lane-
//     linear LDS dest (slot v = tid + round*384), single vmcnt drain at the
//     barrier. All lanes stay active (v clamped to tot-1; duplicate writes
//     land in never-read pad slots; LDS padded to 1536 float4).
//   - Compact domain Lz*Ly*5 (y>=Ly rows gone) via magic-mul division by Ly
//     (Ly in [4,17]; zy<=288 -> 24-bit magic exact, uniform, once/block).
//   - Pooling unchanged except plane stride is now Ly*XPAD (compact layout).
//
// f:         (B=2, C=128, 32, 64, 64) float32
// proposals: (N=32, 8) float32 = [b, score, cz, cy, cx, sz, sy, sx]
// out:       (N=32, C=128, 7, 7, 7) float32
//
// Reference semantics:
//   c0 = max(floor((center - side/2)/4), 0); c1 = min(ceil((center + side/2)/4), dim)
//   L = c1 - c0  (in [4,17] here); window i = [i*L//7, ceil((i+1)*L/7)), width 1..4.

constexpr int C_CH = 128;
constexpr int FD = 32, FH = 64, FW = 64;
constexpr int CH_VOL = FD * FH * FW;        // 131072
constexpr int LMAX = 17;
constexpr int XPAD = 20;                    // 17 + up to 3 alignment shift
constexpr int VQ   = XPAD / 4;              // 5 float4 per row
constexpr int THREADS = 384;                // 6 waves; 343 outputs in one round
// LDS float4 capacity padded to a full number of staging rounds so tail-wave
// lane-linear global_load_lds writes stay in bounds: ceil(17*17*5/384)*384.
constexpr int MAXQ = ((LMAX * LMAX * VQ + THREADS - 1) / THREADS) * THREADS; // 1536

__device__ __forceinline__ void gload_lds16(const void* g, void* l) {
    __builtin_amdgcn_global_load_lds(
        (const __attribute__((address_space(1))) unsigned int*)g,
        (__attribute__((address_space(3))) unsigned int*)l, 16, 0, 0);
}

__global__ __launch_bounds__(THREADS) void crop_roi_kernel(
    const float* __restrict__ f,
    const float* __restrict__ proposals,
    float* __restrict__ out)
{
    __shared__ __align__(16) float lds[MAXQ * 4];      // 24576 B
    __shared__ int ws_[3][7], we_[3][7];

    const int n = blockIdx.x;               // proposal
    const int c = blockIdx.y;               // channel

    const float* p = proposals + n * 8;
    const int   b  = (int)p[0];
    const float cz = p[2], cy = p[3], cx = p[4];
    const float sz = p[5], sy = p[6], sx = p[7];

    const int c0z = max((int)floorf((cz - sz * 0.5f) * 0.25f), 0);
    const int c0y = max((int)floorf((cy - sy * 0.5f) * 0.25f), 0);
    const int c0x = max((int)floorf((cx - sx * 0.5f) * 0.25f), 0);
    const int c1z = min((int)ceilf((cz + sz * 0.5f) * 0.25f), FD);
    const int c1y = min((int)ceilf((cy + sy * 0.5f) * 0.25f), FH);
    const int c1x = min((int)ceilf((cx + sx * 0.5f) * 0.25f), FW);
    const int Lz = c1z - c0z, Ly = c1y - c0y, Lx = c1x - c0x;

    // window-bound table: 21 threads compute, all read via LDS
    if (threadIdx.x < 21) {
        const int d = threadIdx.x / 7;      // 0=z, 1=y, 2=x
        const int i = threadIdx.x % 7;
        const int L = (d == 0) ? Lz : (d == 1) ? Ly : Lx;
        ws_[d][i] = (i * L) / 7;
        we_[d][i] = ((i + 1) * L + 6) / 7;
    }

    // ---- async float4 staging, compact domain Lz*Ly*VQ ----
    const int ax0    = c0x & ~3;
    const int shift  = c0x - ax0;                 // 0..3
    const int nvecm1 = ((shift + Lx + 3) >> 2) - 1;   // last valid float4 per row

    const float4* f4 = reinterpret_cast<const float4*>(
        f + (size_t)(b * C_CH + c) * CH_VOL + c0z * (FH * FW) + c0y * FW + ax0);
    float4* lds4 = reinterpret_cast<float4*>(lds);

    // magic divisor for zy / Ly: exact for zy <= 288 since
    // zy*(Ly - 2^24 mod Ly) <= 288*16 << 2^24; zy*Mly < 2^32 for Ly >= 4.
    const unsigned Mly = 16777216u / (unsigned)Ly + 1u;   // uniform, once/block
    const int tot = Lz * Ly * VQ;                 // <= 1445 float4 slots

    for (int base = 0; base < tot; base += THREADS) {
        // all lanes active every round: clamp keeps (z,y,q) valid; HW writes
        // LDS at wave-uniform base + lane*16 regardless, inside MAXQ pad.
        const unsigned v  = (unsigned)min(base + (int)threadIdx.x, tot - 1);
        const unsigned zy = v / 5u;               // compile-time magic
        const int q  = (int)(v - zy * 5u);
        const int z  = (int)((zy * Mly) >> 24);   // zy / Ly
        const int y  = (int)zy - z * Ly;
        const int qc = min(q, nvecm1);            // stay inside source row (16B aligned)
        gload_lds16(f4 + (z * (FH * FW / 4) + y * (FW / 4) + qc),
                    lds4 + (base + (int)threadIdx.x));
    }
    __syncthreads();   // drains vmcnt(0): all LDS writes visible

    // ---- pooling: one output per lane, single round ----
    const int r = threadIdx.x;
    if (r < 343) {
        const int iz = r / 49, iy = (r / 7) % 7, ix = r % 7;
        const int zs = ws_[0][iz], ze = we_[0][iz];
        const int ys = ws_[1][iy], ye = we_[1][iy];
        const int xs = ws_[2][ix] + shift, xm = we_[2][ix] - 1 + shift;
        const int x1 = min(xs + 1, xm);     // clamped 4-wide x window
        const int x2 = min(xs + 2, xm);     // (duplicates harmless under max)
        const int x3 = min(xs + 3, xm);

        float m = -INFINITY;
        for (int z = zs; z < ze; ++z) {
            const float* Pz = lds + (z * Ly) * XPAD;   // compact plane stride
            for (int y = ys; y < ye; ++y) {
                const float* Lp = Pz + y * XPAD;
                // two triple-max shapes -> v_max3_f32 x2
                const float t = fmaxf(fmaxf(Lp[xs], Lp[x1]), Lp[x2]);
                m = fmaxf(fmaxf(t, Lp[x3]), m);
            }
        }
        out[(size_t)(n * C_CH + c) * 343 + r] = m;
    }
}

extern "C" void kernel_launch(void* const* d_in, const int* in_sizes, int n_in,
                              void* d_out, int out_size, void* d_ws, size_t ws_size,
                              hipStream_t stream) {
    const float* f         = (const float*)d_in[0];
    // d_in[1] = `inputs` zeros tensor — shape-only in the reference; unused.
    const float* proposals = (const float*)d_in[2];
    float* out             = (float*)d_out;

    dim3 grid(32, C_CH);     // 32 proposals x 128 channels = 4096 blocks
    crop_roi_kernel<<<grid, THREADS, 0, stream>>>(f, proposals, out);
}